// Round 1
// baseline (1406.619 us; speedup 1.0000x reference)
//
#include <hip/hip_runtime.h>
#include <math.h>

// Problem constants (B=4, S=1024, E=512, H=8, D=64, T_MAX=20)
#define SEQ   1024
#define EMB   512
#define NROWS 4096   // B*S
#define NTILE 16     // K-tiles of 64 in attention (SEQ/64)

// ---------------------------------------------------------------------------
// K0: gate + complexity MLPs -> T_i[4096]. One block (128 threads) per row.
// All internal math in f64 to pin the ceil() discretization to the np ref.
// ---------------------------------------------------------------------------
__global__ __launch_bounds__(128) void gates_kernel(
    const float* __restrict__ x,
    const float* __restrict__ gW1, const float* __restrict__ gb1,
    const float* __restrict__ gg,  const float* __restrict__ gbe,
    const float* __restrict__ gW2, const float* __restrict__ gb2,
    const float* __restrict__ gW3, const float* __restrict__ gb3,
    const float* __restrict__ cW1, const float* __restrict__ cb1,
    const float* __restrict__ cg,  const float* __restrict__ cbe,
    const float* __restrict__ cW2, const float* __restrict__ cb2,
    const float* __restrict__ cW3, const float* __restrict__ cb3,
    int* __restrict__ T_i)
{
    __shared__ double xs[EMB];
    __shared__ double h1[128];
    __shared__ double h2[64];
    __shared__ double rbuf[128];
    __shared__ double stats[2];

    const int row = blockIdx.x;
    const int tid = threadIdx.x;

    for (int ii = tid; ii < EMB; ii += 128) xs[ii] = (double)x[row * EMB + ii];
    __syncthreads();

    double outs[2];
    for (int br = 0; br < 2; ++br) {
        const float *W1, *b1, *gam, *bet, *W2, *b2, *W3, *b3;
        int H1, H2;
        if (br == 0) { W1=gW1; b1=gb1; gam=gg; bet=gbe; W2=gW2; b2=gb2; W3=gW3; b3=gb3; H1=128; H2=64; }
        else         { W1=cW1; b1=cb1; gam=cg; bet=cbe; W2=cW2; b2=cb2; W3=cW3; b3=cb3; H1=64;  H2=32; }

        // h1 = x @ W1 + b1
        if (tid < H1) {
            double acc = (double)b1[tid];
            for (int k = 0; k < EMB; ++k) acc += xs[k] * (double)W1[k * H1 + tid];
            h1[tid] = acc;
        }
        __syncthreads();

        // LayerNorm over H1 (mean, then var = mean((h-mu)^2))
        rbuf[tid] = (tid < H1) ? h1[tid] : 0.0;
        __syncthreads();
        for (int off = 64; off >= 1; off >>= 1) { if (tid < off) rbuf[tid] += rbuf[tid + off]; __syncthreads(); }
        if (tid == 0) stats[0] = rbuf[0] / (double)H1;
        __syncthreads();
        const double mu = stats[0];
        rbuf[tid] = (tid < H1) ? (h1[tid] - mu) * (h1[tid] - mu) : 0.0;
        __syncthreads();
        for (int off = 64; off >= 1; off >>= 1) { if (tid < off) rbuf[tid] += rbuf[tid + off]; __syncthreads(); }
        if (tid == 0) stats[1] = rbuf[0] / (double)H1;
        __syncthreads();
        const double var = stats[1];
        if (tid < H1) {
            double hn = (h1[tid] - mu) / sqrt(var + 1e-5) * (double)gam[tid] + (double)bet[tid];
            h1[tid] = hn > 0.0 ? hn : 0.0;   // ReLU
        }
        __syncthreads();

        // h2 = relu(h1 @ W2 + b2)
        if (tid < H2) {
            double acc = (double)b2[tid];
            for (int k = 0; k < H1; ++k) acc += h1[k] * (double)W2[k * H2 + tid];
            h2[tid] = acc > 0.0 ? acc : 0.0;
        }
        __syncthreads();

        // scalar = sigmoid(h2 @ W3 + b3)
        rbuf[tid] = (tid < H2) ? h2[tid] * (double)W3[tid] : 0.0;
        __syncthreads();
        for (int off = 64; off >= 1; off >>= 1) { if (tid < off) rbuf[tid] += rbuf[tid + off]; __syncthreads(); }
        if (tid == 0) {
            double z = rbuf[0] + (double)b3[0];
            stats[0] = 1.0 / (1.0 + exp(-z));
        }
        __syncthreads();
        outs[br] = stats[0];
        __syncthreads();
    }

    if (tid == 0) {
        const int s = row & (SEQ - 1);
        const double step = (1.2 - 0.8) / (double)(SEQ - 1);   // np.linspace step
        const double pos  = (double)s * step + 0.8;
        const double score = ((1.0 - 0.3) * outs[0] + 0.3 * outs[1]) * pos;
        double t = ceil(score * 20.0);
        t = t < 1.0 ? 1.0 : (t > 20.0 ? 20.0 : t);
        T_i[row] = (int)t;
    }
}

// ---------------------------------------------------------------------------
// K1: fused QKV GEMM (f64 accumulate) + LIF spike recurrence epilogue.
// Grid: (N/64, M/64, 3). 256 threads, 64x64 tile, BK=16, 4x4 per thread.
// ---------------------------------------------------------------------------
__global__ __launch_bounds__(256) void qkv_lif_kernel(
    const float* __restrict__ x,
    const float* __restrict__ Wq, const float* __restrict__ Wk, const float* __restrict__ Wv,
    const float* __restrict__ aq, const float* __restrict__ bq,
    const float* __restrict__ akp, const float* __restrict__ bkp,
    const float* __restrict__ av, const float* __restrict__ bv,
    const int* __restrict__ T_i,
    float* __restrict__ q_sum, float* __restrict__ k_sum, float* __restrict__ v_mean)
{
    const int z = blockIdx.z;
    const float* __restrict__ W = (z == 0) ? Wq : (z == 1) ? Wk : Wv;
    float* __restrict__ out     = (z == 0) ? q_sum : (z == 1) ? k_sum : v_mean;
    const double alpha = (double)((z == 0) ? aq : (z == 1) ? akp : av)[0];
    const double beta  = (double)((z == 0) ? bq : (z == 1) ? bkp : bv)[0];

    __shared__ float As[64][17];
    __shared__ float Bs[16][65];

    const int tid = threadIdx.x;
    const int tx = tid & 15, ty = tid >> 4;
    const int row0 = blockIdx.y * 64, col0 = blockIdx.x * 64;

    double acc[4][4];
    #pragma unroll
    for (int i = 0; i < 4; ++i)
        #pragma unroll
        for (int j = 0; j < 4; ++j) acc[i][j] = 0.0;

    const int ar  = tid >> 2, ak4 = (tid & 3) * 4;   // A-tile load coords
    const int bkr = tid >> 4, bn4 = (tid & 15) * 4;  // B-tile load coords

    for (int k0 = 0; k0 < EMB; k0 += 16) {
        const float4 a4 = *(const float4*)&x[(size_t)(row0 + ar) * EMB + k0 + ak4];
        As[ar][ak4 + 0] = a4.x; As[ar][ak4 + 1] = a4.y;
        As[ar][ak4 + 2] = a4.z; As[ar][ak4 + 3] = a4.w;
        const float4 b4 = *(const float4*)&W[(size_t)(k0 + bkr) * EMB + col0 + bn4];
        Bs[bkr][bn4 + 0] = b4.x; Bs[bkr][bn4 + 1] = b4.y;
        Bs[bkr][bn4 + 2] = b4.z; Bs[bkr][bn4 + 3] = b4.w;
        __syncthreads();
        #pragma unroll
        for (int kk = 0; kk < 16; ++kk) {
            float a[4], b[4];
            #pragma unroll
            for (int i = 0; i < 4; ++i) a[i] = As[ty * 4 + i][kk];
            #pragma unroll
            for (int j = 0; j < 4; ++j) b[j] = Bs[kk][tx * 4 + j];
            #pragma unroll
            for (int i = 0; i < 4; ++i)
                #pragma unroll
                for (int j = 0; j < 4; ++j) acc[i][j] += (double)a[i] * (double)b[j];
        }
        __syncthreads();
    }

    // LIF epilogue: spike_sum(acc, T) computed per element in f64
    #pragma unroll
    for (int i = 0; i < 4; ++i) {
        const int r = row0 + ty * 4 + i;
        const int T = T_i[r];
        #pragma unroll
        for (int j = 0; j < 4; ++j) {
            const double xv = acc[i][j];
            double cur = 0.0, vm = 0.0, spikes = 0.0;
            for (int t = 0; t < T; ++t) {
                cur = alpha * cur + xv;
                vm  = beta * vm + cur;
                if (vm >= 1.0) { spikes += 1.0; vm = 0.0; }
            }
            if (z == 2) spikes = spikes / 20.0;   // v_mean = acc / T_MAX
            out[(size_t)r * EMB + col0 + tx * 4 + j] = (float)spikes;
        }
    }
}

// ---------------------------------------------------------------------------
// K2: attention. One block per (b, h, 8 query rows). Scores are EXACT in f32
// (integer spike counts), full-row softmax in LDS, PV accumulate in f32.
// ---------------------------------------------------------------------------
__global__ __launch_bounds__(256) void attn_kernel(
    const float* __restrict__ q_sum, const float* __restrict__ k_sum,
    const float* __restrict__ v_mean, float* __restrict__ attn)
{
    __shared__ float sc[8][SEQ];     // 32 KB
    __shared__ float kv[64][65];     // 16.6 KB, pad 65 -> 2-way (free)
    __shared__ float qt[8][64];
    __shared__ float sstat[8];

    const int b = blockIdx.z, h = blockIdx.y;
    const int i0 = blockIdx.x * 8;
    const int tid = threadIdx.x;

    const float* __restrict__ Q = q_sum + (size_t)b * SEQ * EMB + h * 64;
    const float* __restrict__ K = k_sum + (size_t)b * SEQ * EMB + h * 64;
    const float* __restrict__ V = v_mean + (size_t)b * SEQ * EMB + h * 64;

    for (int idx = tid; idx < 512; idx += 256) {
        const int r = idx >> 6, d = idx & 63;
        qt[r][d] = Q[(size_t)(i0 + r) * EMB + d];
    }
    __syncthreads();

    // Phase 1: scores
    {
        const int j = tid & 63, rp = tid >> 6;      // rp 0..3 -> rows 2rp, 2rp+1
        const int r0 = rp * 2, r1 = rp * 2 + 1;
        for (int jt = 0; jt < NTILE; ++jt) {
            #pragma unroll
            for (int c = 0; c < 16; ++c) {
                const int idx = c * 256 + tid;
                const int jj = idx >> 6, d = idx & 63;
                kv[jj][d] = K[(size_t)(jt * 64 + jj) * EMB + d];
            }
            __syncthreads();
            float s0 = 0.f, s1 = 0.f;
            #pragma unroll
            for (int d = 0; d < 64; ++d) {
                const float kvv = kv[j][d];
                s0 += qt[r0][d] * kvv;
                s1 += qt[r1][d] * kvv;
            }
            sc[r0][jt * 64 + j] = s0 * 0.125f;
            sc[r1][jt * 64 + j] = s1 * 0.125f;
            __syncthreads();
        }
    }

    // Phase 2: softmax per row (8 rows x 32 lanes)
    {
        const int r = tid >> 5, l = tid & 31;
        float m = -INFINITY;
        for (int c = l; c < SEQ; c += 32) m = fmaxf(m, sc[r][c]);
        #pragma unroll
        for (int off = 16; off; off >>= 1) m = fmaxf(m, __shfl_xor(m, off, 32));
        float sum = 0.f;
        for (int c = l; c < SEQ; c += 32) {
            const float e = __expf(sc[r][c] - m);
            sc[r][c] = e;
            sum += e;
        }
        #pragma unroll
        for (int off = 16; off; off >>= 1) sum += __shfl_xor(sum, off, 32);
        if (l == 0) sstat[r] = 1.0f / sum;
    }
    __syncthreads();

    // Phase 3: PV
    {
        const int d = tid & 63, r0 = tid >> 6;       // rows r0 and r0+4
        float a0 = 0.f, a1 = 0.f;
        for (int jt = 0; jt < NTILE; ++jt) {
            #pragma unroll
            for (int c = 0; c < 16; ++c) {
                const int idx = c * 256 + tid;
                const int jj = idx >> 6, dd = idx & 63;
                kv[jj][dd] = V[(size_t)(jt * 64 + jj) * EMB + dd];
            }
            __syncthreads();
            #pragma unroll
            for (int jj = 0; jj < 64; ++jj) {
                const float vv = kv[jj][d];
                a0 += sc[r0][jt * 64 + jj] * vv;
                a1 += sc[r0 + 4][jt * 64 + jj] * vv;
            }
            __syncthreads();
        }
        attn[((size_t)b * SEQ + i0 + r0) * EMB + h * 64 + d]     = a0 * sstat[r0];
        attn[((size_t)b * SEQ + i0 + r0 + 4) * EMB + h * 64 + d] = a1 * sstat[r0 + 4];
    }
}

// ---------------------------------------------------------------------------
// K3: out = attn @ Wo + bo (f32). Same tiling as K1.
// ---------------------------------------------------------------------------
__global__ __launch_bounds__(256) void out_gemm_kernel(
    const float* __restrict__ A, const float* __restrict__ W,
    const float* __restrict__ bias, float* __restrict__ out)
{
    __shared__ float As[64][17];
    __shared__ float Bs[16][65];

    const int tid = threadIdx.x;
    const int tx = tid & 15, ty = tid >> 4;
    const int row0 = blockIdx.y * 64, col0 = blockIdx.x * 64;

    float acc[4][4];
    #pragma unroll
    for (int i = 0; i < 4; ++i)
        #pragma unroll
        for (int j = 0; j < 4; ++j) acc[i][j] = 0.f;

    const int ar  = tid >> 2, ak4 = (tid & 3) * 4;
    const int bkr = tid >> 4, bn4 = (tid & 15) * 4;

    for (int k0 = 0; k0 < EMB; k0 += 16) {
        const float4 a4 = *(const float4*)&A[(size_t)(row0 + ar) * EMB + k0 + ak4];
        As[ar][ak4 + 0] = a4.x; As[ar][ak4 + 1] = a4.y;
        As[ar][ak4 + 2] = a4.z; As[ar][ak4 + 3] = a4.w;
        const float4 b4 = *(const float4*)&W[(size_t)(k0 + bkr) * EMB + col0 + bn4];
        Bs[bkr][bn4 + 0] = b4.x; Bs[bkr][bn4 + 1] = b4.y;
        Bs[bkr][bn4 + 2] = b4.z; Bs[bkr][bn4 + 3] = b4.w;
        __syncthreads();
        #pragma unroll
        for (int kk = 0; kk < 16; ++kk) {
            float a[4], b[4];
            #pragma unroll
            for (int i = 0; i < 4; ++i) a[i] = As[ty * 4 + i][kk];
            #pragma unroll
            for (int j = 0; j < 4; ++j) b[j] = Bs[kk][tx * 4 + j];
            #pragma unroll
            for (int i = 0; i < 4; ++i)
                #pragma unroll
                for (int j = 0; j < 4; ++j) acc[i][j] += a[i] * b[j];
        }
        __syncthreads();
    }

    #pragma unroll
    for (int i = 0; i < 4; ++i) {
        const int r = row0 + ty * 4 + i;
        #pragma unroll
        for (int j = 0; j < 4; ++j) {
            const int c = col0 + tx * 4 + j;
            out[(size_t)r * EMB + c] = acc[i][j] + bias[c];
        }
    }
}

// ---------------------------------------------------------------------------
extern "C" void kernel_launch(void* const* d_in, const int* in_sizes, int n_in,
                              void* d_out, int out_size, void* d_ws, size_t ws_size,
                              hipStream_t stream)
{
    const float* x   = (const float*)d_in[0];
    const float* Wq  = (const float*)d_in[1];
    const float* Wk  = (const float*)d_in[2];
    const float* Wv  = (const float*)d_in[3];
    const float* Wo  = (const float*)d_in[4];
    const float* bo  = (const float*)d_in[5];
    const float* gW1 = (const float*)d_in[6];
    const float* gb1 = (const float*)d_in[7];
    const float* gg  = (const float*)d_in[8];
    const float* gbe = (const float*)d_in[9];
    const float* gW2 = (const float*)d_in[10];
    const float* gb2 = (const float*)d_in[11];
    const float* gW3 = (const float*)d_in[12];
    const float* gb3 = (const float*)d_in[13];
    const float* cW1 = (const float*)d_in[14];
    const float* cb1 = (const float*)d_in[15];
    const float* cg  = (const float*)d_in[16];
    const float* cbe = (const float*)d_in[17];
    const float* cW2 = (const float*)d_in[18];
    const float* cb2 = (const float*)d_in[19];
    const float* cW3 = (const float*)d_in[20];
    const float* cb3 = (const float*)d_in[21];
    const float* aq  = (const float*)d_in[22];
    const float* bq  = (const float*)d_in[23];
    const float* ak  = (const float*)d_in[24];
    const float* bk  = (const float*)d_in[25];
    const float* av  = (const float*)d_in[26];
    const float* bv  = (const float*)d_in[27];

    int*   Tp     = (int*)d_ws;
    float* fws    = (float*)d_ws;
    float* q_sum  = fws + 4096;
    float* k_sum  = q_sum + (size_t)NROWS * EMB;
    float* v_mean = k_sum + (size_t)NROWS * EMB;
    float* attn   = v_mean + (size_t)NROWS * EMB;
    float* out    = (float*)d_out;

    gates_kernel<<<dim3(NROWS), dim3(128), 0, stream>>>(
        x, gW1, gb1, gg, gbe, gW2, gb2, gW3, gb3,
        cW1, cb1, cg, cbe, cW2, cb2, cW3, cb3, Tp);

    qkv_lif_kernel<<<dim3(EMB / 64, NROWS / 64, 3), dim3(256), 0, stream>>>(
        x, Wq, Wk, Wv, aq, bq, ak, bk, av, bv, Tp, q_sum, k_sum, v_mean);

    attn_kernel<<<dim3(SEQ / 8, 8, 4), dim3(256), 0, stream>>>(
        q_sum, k_sum, v_mean, attn);

    out_gemm_kernel<<<dim3(EMB / 64, NROWS / 64), dim3(256), 0, stream>>>(
        attn, Wo, bo, out);
}

// Round 2
// 468.550 us; speedup vs baseline: 3.0021x; 3.0021x over previous
//
#include <hip/hip_runtime.h>
#include <math.h>

// Problem constants (B=4, S=1024, E=512, H=8, D=64, T_MAX=20)
#define SEQ   1024
#define EMB   512
#define NROWS 4096   // B*S
#define LDP   72     // LDS row stride (bf16 elems): 144 B, 16B-aligned, bank-spread

typedef __attribute__((ext_vector_type(8))) short short8;   // bf16 x8 MFMA frag
typedef __attribute__((ext_vector_type(4))) float float4v;  // f32 x4 MFMA acc

__device__ __forceinline__ float bf2f(unsigned short s) {
    union { float f; unsigned u; } x; x.u = ((unsigned)s) << 16; return x.f;
}
__device__ __forceinline__ unsigned short f2bf(float f) {
    union { float f; unsigned u; } x; x.f = f;
    unsigned r = x.u + 0x7fffu + ((x.u >> 16) & 1u);   // round-to-nearest-even
    return (unsigned short)(r >> 16);
}

// ---------------------------------------------------------------------------
// K0: gate + complexity MLPs -> T_i[4096]. One block (128 threads) per row.
// All internal math in f64 to pin the ceil() discretization to the np ref.
// ---------------------------------------------------------------------------
__global__ __launch_bounds__(128) void gates_kernel(
    const float* __restrict__ x,
    const float* __restrict__ gW1, const float* __restrict__ gb1,
    const float* __restrict__ gg,  const float* __restrict__ gbe,
    const float* __restrict__ gW2, const float* __restrict__ gb2,
    const float* __restrict__ gW3, const float* __restrict__ gb3,
    const float* __restrict__ cW1, const float* __restrict__ cb1,
    const float* __restrict__ cg,  const float* __restrict__ cbe,
    const float* __restrict__ cW2, const float* __restrict__ cb2,
    const float* __restrict__ cW3, const float* __restrict__ cb3,
    int* __restrict__ T_i)
{
    __shared__ double xs[EMB];
    __shared__ double h1[128];
    __shared__ double h2[64];
    __shared__ double rbuf[128];
    __shared__ double stats[2];

    const int row = blockIdx.x;
    const int tid = threadIdx.x;

    for (int ii = tid; ii < EMB; ii += 128) xs[ii] = (double)x[row * EMB + ii];
    __syncthreads();

    double outs[2];
    for (int br = 0; br < 2; ++br) {
        const float *W1, *b1, *gam, *bet, *W2, *b2, *W3, *b3;
        int H1, H2;
        if (br == 0) { W1=gW1; b1=gb1; gam=gg; bet=gbe; W2=gW2; b2=gb2; W3=gW3; b3=gb3; H1=128; H2=64; }
        else         { W1=cW1; b1=cb1; gam=cg; bet=cbe; W2=cW2; b2=cb2; W3=cW3; b3=cb3; H1=64;  H2=32; }

        if (tid < H1) {
            double acc = (double)b1[tid];
            for (int k = 0; k < EMB; ++k) acc += xs[k] * (double)W1[k * H1 + tid];
            h1[tid] = acc;
        }
        __syncthreads();

        rbuf[tid] = (tid < H1) ? h1[tid] : 0.0;
        __syncthreads();
        for (int off = 64; off >= 1; off >>= 1) { if (tid < off) rbuf[tid] += rbuf[tid + off]; __syncthreads(); }
        if (tid == 0) stats[0] = rbuf[0] / (double)H1;
        __syncthreads();
        const double mu = stats[0];
        rbuf[tid] = (tid < H1) ? (h1[tid] - mu) * (h1[tid] - mu) : 0.0;
        __syncthreads();
        for (int off = 64; off >= 1; off >>= 1) { if (tid < off) rbuf[tid] += rbuf[tid + off]; __syncthreads(); }
        if (tid == 0) stats[1] = rbuf[0] / (double)H1;
        __syncthreads();
        const double var = stats[1];
        if (tid < H1) {
            double hn = (h1[tid] - mu) / sqrt(var + 1e-5) * (double)gam[tid] + (double)bet[tid];
            h1[tid] = hn > 0.0 ? hn : 0.0;
        }
        __syncthreads();

        if (tid < H2) {
            double acc = (double)b2[tid];
            for (int k = 0; k < H1; ++k) acc += h1[k] * (double)W2[k * H2 + tid];
            h2[tid] = acc > 0.0 ? acc : 0.0;
        }
        __syncthreads();

        rbuf[tid] = (tid < H2) ? h2[tid] * (double)W3[tid] : 0.0;
        __syncthreads();
        for (int off = 64; off >= 1; off >>= 1) { if (tid < off) rbuf[tid] += rbuf[tid + off]; __syncthreads(); }
        if (tid == 0) {
            double z = rbuf[0] + (double)b3[0];
            stats[0] = 1.0 / (1.0 + exp(-z));
        }
        __syncthreads();
        outs[br] = stats[0];
        __syncthreads();
    }

    if (tid == 0) {
        const int s = row & (SEQ - 1);
        const double step = (1.2 - 0.8) / (double)(SEQ - 1);
        const double pos  = (double)s * step + 0.8;
        const double score = ((1.0 - 0.3) * outs[0] + 0.3 * outs[1]) * pos;
        double t = ceil(score * 20.0);
        t = t < 1.0 ? 1.0 : (t > 20.0 ? 20.0 : t);
        T_i[row] = (int)t;
    }
}

// ---------------------------------------------------------------------------
// K1: fused QKV GEMM (f64 accumulate) + LIF spike recurrence epilogue.
// Outputs bf16: q_sum/k_sum are exact small integers; v_mean = spikes/20.
// ---------------------------------------------------------------------------
__global__ __launch_bounds__(256) void qkv_lif_kernel(
    const float* __restrict__ x,
    const float* __restrict__ Wq, const float* __restrict__ Wk, const float* __restrict__ Wv,
    const float* __restrict__ aq, const float* __restrict__ bq,
    const float* __restrict__ akp, const float* __restrict__ bkp,
    const float* __restrict__ av, const float* __restrict__ bv,
    const int* __restrict__ T_i,
    unsigned short* __restrict__ q_sum, unsigned short* __restrict__ k_sum,
    unsigned short* __restrict__ v_mean)
{
    const int z = blockIdx.z;
    const float* __restrict__ W = (z == 0) ? Wq : (z == 1) ? Wk : Wv;
    unsigned short* __restrict__ out = (z == 0) ? q_sum : (z == 1) ? k_sum : v_mean;
    const double alpha = (double)((z == 0) ? aq : (z == 1) ? akp : av)[0];
    const double beta  = (double)((z == 0) ? bq : (z == 1) ? bkp : bv)[0];

    __shared__ float As[64][17];
    __shared__ float Bs[16][65];

    const int tid = threadIdx.x;
    const int tx = tid & 15, ty = tid >> 4;
    const int row0 = blockIdx.y * 64, col0 = blockIdx.x * 64;

    double acc[4][4];
    #pragma unroll
    for (int i = 0; i < 4; ++i)
        #pragma unroll
        for (int j = 0; j < 4; ++j) acc[i][j] = 0.0;

    const int ar  = tid >> 2, ak4 = (tid & 3) * 4;
    const int bkr = tid >> 4, bn4 = (tid & 15) * 4;

    for (int k0 = 0; k0 < EMB; k0 += 16) {
        const float4 a4 = *(const float4*)&x[(size_t)(row0 + ar) * EMB + k0 + ak4];
        As[ar][ak4 + 0] = a4.x; As[ar][ak4 + 1] = a4.y;
        As[ar][ak4 + 2] = a4.z; As[ar][ak4 + 3] = a4.w;
        const float4 b4 = *(const float4*)&W[(size_t)(k0 + bkr) * EMB + col0 + bn4];
        Bs[bkr][bn4 + 0] = b4.x; Bs[bkr][bn4 + 1] = b4.y;
        Bs[bkr][bn4 + 2] = b4.z; Bs[bkr][bn4 + 3] = b4.w;
        __syncthreads();
        #pragma unroll
        for (int kk = 0; kk < 16; ++kk) {
            float a[4], b[4];
            #pragma unroll
            for (int i = 0; i < 4; ++i) a[i] = As[ty * 4 + i][kk];
            #pragma unroll
            for (int j = 0; j < 4; ++j) b[j] = Bs[kk][tx * 4 + j];
            #pragma unroll
            for (int i = 0; i < 4; ++i)
                #pragma unroll
                for (int j = 0; j < 4; ++j) acc[i][j] += (double)a[i] * (double)b[j];
        }
        __syncthreads();
    }

    #pragma unroll
    for (int i = 0; i < 4; ++i) {
        const int r = row0 + ty * 4 + i;
        const int T = T_i[r];
        ushort4 pack;
        unsigned short* pk = (unsigned short*)&pack;
        #pragma unroll
        for (int j = 0; j < 4; ++j) {
            const double xv = acc[i][j];
            double cur = 0.0, vm = 0.0, spikes = 0.0;
            for (int t = 0; t < T; ++t) {
                cur = alpha * cur + xv;
                vm  = beta * vm + cur;
                if (vm >= 1.0) { spikes += 1.0; vm = 0.0; }
            }
            if (z == 2) spikes = spikes / 20.0;
            pk[j] = f2bf((float)spikes);
        }
        *(ushort4*)&out[(size_t)r * EMB + col0 + tx * 4] = pack;
    }
}

// ---------------------------------------------------------------------------
// K2: fused flash-style MFMA attention. Block = (b, h, 64 Q-rows), 4 waves.
// QK^T exact in bf16 MFMA (integer spike counts, scale 1/8 folded into Q).
// Online softmax per row; P->LDS->A-frag round trip; V staged transposed
// with XOR chunk swizzle (conflict-optimal ds_read_b128 everywhere).
// ---------------------------------------------------------------------------
__global__ __launch_bounds__(256) void attn_mfma_kernel(
    const unsigned short* __restrict__ q, const unsigned short* __restrict__ k,
    const unsigned short* __restrict__ v, float* __restrict__ attn)
{
    __shared__ __align__(16) short Ks[64 * LDP];
    __shared__ __align__(16) short Pt[64 * LDP];
    __shared__ __align__(16) short Vt[64 * LDP];

    const int b = blockIdx.z, h = blockIdx.y;
    const int i0 = blockIdx.x * 64;
    const int tid  = threadIdx.x;
    const int wave = tid >> 6, lane = tid & 63;
    const int quad = lane >> 4, c = lane & 15;

    const unsigned short* Qb = q + ((size_t)b * SEQ + i0) * EMB + h * 64;
    const unsigned short* Kb = k + (size_t)b * SEQ * EMB + h * 64;
    const unsigned short* Vb = v + (size_t)b * SEQ * EMB + h * 64;

    // Q A-fragments for this wave's 16 rows, pre-scaled by 1/8 (exact: pow2)
    short8 qf[2];
    {
        const int qrow = wave * 16 + c;
        #pragma unroll
        for (int ks = 0; ks < 2; ++ks) {
            short8 raw = *(const short8*)(Qb + (size_t)qrow * EMB + ks * 32 + quad * 8);
            short8 sc8;
            #pragma unroll
            for (int j = 0; j < 8; ++j)
                sc8[j] = (short)f2bf(bf2f((unsigned short)raw[j]) * 0.125f);
            qf[ks] = sc8;
        }
    }

    float m_r[4], l_r[4];
    float4v o[4];
    #pragma unroll
    for (int r = 0; r < 4; ++r) { m_r[r] = -1e30f; l_r[r] = 0.f; }
    #pragma unroll
    for (int nb = 0; nb < 4; ++nb)
        #pragma unroll
        for (int r = 0; r < 4; ++r) o[nb][r] = 0.f;

    for (int jt = 0; jt < SEQ / 64; ++jt) {
        // ---- stage K tile (64x64 bf16) ----
        #pragma unroll
        for (int it = 0; it < 2; ++it) {
            const int idx = it * 256 + tid;          // 0..511 16B-chunks
            const int row = idx >> 3, ch = idx & 7;
            short8 val = *(const short8*)(Kb + (size_t)(jt * 64 + row) * EMB + ch * 8);
            *(short8*)&Ks[row * LDP + ch * 8] = val;
        }
        __syncthreads();

        // ---- scores: S = (Q/8) K^T, exact ----
        float sc[4][4];                              // [nb][reg]
        #pragma unroll
        for (int nb = 0; nb < 4; ++nb) {
            float4v acc = {0.f, 0.f, 0.f, 0.f};
            #pragma unroll
            for (int ks = 0; ks < 2; ++ks) {
                short8 bfrag = *(const short8*)&Ks[(nb * 16 + c) * LDP + ks * 32 + quad * 8];
                acc = __builtin_amdgcn_mfma_f32_16x16x32_bf16(qf[ks], bfrag, acc, 0, 0, 0);
            }
            #pragma unroll
            for (int r = 0; r < 4; ++r) sc[nb][r] = acc[r];
        }

        // ---- online softmax (rows quad*4+r, 16 lanes per quad share a row set) ----
        float mnew[4], alpha[4];
        #pragma unroll
        for (int r = 0; r < 4; ++r) {
            float mx = fmaxf(fmaxf(sc[0][r], sc[1][r]), fmaxf(sc[2][r], sc[3][r]));
            #pragma unroll
            for (int off = 8; off >= 1; off >>= 1) mx = fmaxf(mx, __shfl_xor(mx, off));
            mnew[r]  = fmaxf(m_r[r], mx);
            alpha[r] = __expf(m_r[r] - mnew[r]);
            m_r[r]   = mnew[r];
        }
        float psum[4] = {0.f, 0.f, 0.f, 0.f};
        #pragma unroll
        for (int nb = 0; nb < 4; ++nb)
            #pragma unroll
            for (int r = 0; r < 4; ++r) {
                float p = __expf(sc[nb][r] - mnew[r]);
                psum[r] += p;
                Pt[(wave * 16 + quad * 4 + r) * LDP + nb * 16 + c] = (short)f2bf(p);
            }
        #pragma unroll
        for (int r = 0; r < 4; ++r) {
            float s = psum[r];
            #pragma unroll
            for (int off = 8; off >= 1; off >>= 1) s += __shfl_xor(s, off);
            l_r[r] = l_r[r] * alpha[r] + s;
            #pragma unroll
            for (int nb = 0; nb < 4; ++nb) o[nb][r] *= alpha[r];
        }

        // ---- stage V transposed with XOR chunk swizzle ----
        // Vt[d][ ((r>>3) ^ (d>>3))*8 + (r&7) ]; write packed row-pairs as b32
        {
            const int m = tid & 7, rp = tid >> 3;    // d-chunk, row-pair
            const int r = rp * 2;
            short8 v0 = *(const short8*)(Vb + (size_t)(jt * 64 + r) * EMB + m * 8);
            short8 v1 = *(const short8*)(Vb + (size_t)(jt * 64 + r + 1) * EMB + m * 8);
            const int rch = r >> 3, rlow = r & 7;
            #pragma unroll
            for (int i = 0; i < 8; ++i) {
                const int d = m * 8 + i;
                const int col = ((rch ^ m) << 3) + rlow;     // d>>3 == m
                *(int*)&Vt[d * LDP + col] =
                    (int)((unsigned)(unsigned short)v0[i] |
                          ((unsigned)(unsigned short)v1[i] << 16));
            }
        }
        __syncthreads();

        // ---- PV: O += P V ----
        short8 pf[2];
        #pragma unroll
        for (int ks = 0; ks < 2; ++ks)
            pf[ks] = *(const short8*)&Pt[(wave * 16 + c) * LDP + ks * 32 + quad * 8];
        #pragma unroll
        for (int nb = 0; nb < 4; ++nb) {
            float4v acc = o[nb];
            #pragma unroll
            for (int ks = 0; ks < 2; ++ks) {
                const int d = nb * 16 + c;
                const int kch = ks * 4 + quad;
                const int col = ((kch ^ (d >> 3)) << 3);
                short8 vfrag = *(const short8*)&Vt[d * LDP + col];
                acc = __builtin_amdgcn_mfma_f32_16x16x32_bf16(pf[ks], vfrag, acc, 0, 0, 0);
            }
            o[nb] = acc;
        }
    }

    // ---- epilogue: O / l ----
    #pragma unroll
    for (int r = 0; r < 4; ++r) {
        const float inv = 1.0f / l_r[r];
        const int row = i0 + wave * 16 + quad * 4 + r;
        #pragma unroll
        for (int nb = 0; nb < 4; ++nb)
            attn[((size_t)b * SEQ + row) * EMB + h * 64 + nb * 16 + c] = o[nb][r] * inv;
    }
}

// ---------------------------------------------------------------------------
// K3: out = attn @ Wo + bo (f32).
// ---------------------------------------------------------------------------
__global__ __launch_bounds__(256) void out_gemm_kernel(
    const float* __restrict__ A, const float* __restrict__ W,
    const float* __restrict__ bias, float* __restrict__ out)
{
    __shared__ float As[64][17];
    __shared__ float Bs[16][65];

    const int tid = threadIdx.x;
    const int tx = tid & 15, ty = tid >> 4;
    const int row0 = blockIdx.y * 64, col0 = blockIdx.x * 64;

    float acc[4][4];
    #pragma unroll
    for (int i = 0; i < 4; ++i)
        #pragma unroll
        for (int j = 0; j < 4; ++j) acc[i][j] = 0.f;

    const int ar  = tid >> 2, ak4 = (tid & 3) * 4;
    const int bkr = tid >> 4, bn4 = (tid & 15) * 4;

    for (int k0 = 0; k0 < EMB; k0 += 16) {
        const float4 a4 = *(const float4*)&A[(size_t)(row0 + ar) * EMB + k0 + ak4];
        As[ar][ak4 + 0] = a4.x; As[ar][ak4 + 1] = a4.y;
        As[ar][ak4 + 2] = a4.z; As[ar][ak4 + 3] = a4.w;
        const float4 b4 = *(const float4*)&W[(size_t)(k0 + bkr) * EMB + col0 + bn4];
        Bs[bkr][bn4 + 0] = b4.x; Bs[bkr][bn4 + 1] = b4.y;
        Bs[bkr][bn4 + 2] = b4.z; Bs[bkr][bn4 + 3] = b4.w;
        __syncthreads();
        #pragma unroll
        for (int kk = 0; kk < 16; ++kk) {
            float a[4], b[4];
            #pragma unroll
            for (int i = 0; i < 4; ++i) a[i] = As[ty * 4 + i][kk];
            #pragma unroll
            for (int j = 0; j < 4; ++j) b[j] = Bs[kk][tx * 4 + j];
            #pragma unroll
            for (int i = 0; i < 4; ++i)
                #pragma unroll
                for (int j = 0; j < 4; ++j) acc[i][j] += a[i] * b[j];
        }
        __syncthreads();
    }

    #pragma unroll
    for (int i = 0; i < 4; ++i) {
        const int r = row0 + ty * 4 + i;
        #pragma unroll
        for (int j = 0; j < 4; ++j) {
            const int c2 = col0 + tx * 4 + j;
            out[(size_t)r * EMB + c2] = acc[i][j] + bias[c2];
        }
    }
}

// ---------------------------------------------------------------------------
extern "C" void kernel_launch(void* const* d_in, const int* in_sizes, int n_in,
                              void* d_out, int out_size, void* d_ws, size_t ws_size,
                              hipStream_t stream)
{
    const float* x   = (const float*)d_in[0];
    const float* Wq  = (const float*)d_in[1];
    const float* Wk  = (const float*)d_in[2];
    const float* Wv  = (const float*)d_in[3];
    const float* Wo  = (const float*)d_in[4];
    const float* bo  = (const float*)d_in[5];
    const float* gW1 = (const float*)d_in[6];
    const float* gb1 = (const float*)d_in[7];
    const float* gg  = (const float*)d_in[8];
    const float* gbe = (const float*)d_in[9];
    const float* gW2 = (const float*)d_in[10];
    const float* gb2 = (const float*)d_in[11];
    const float* gW3 = (const float*)d_in[12];
    const float* gb3 = (const float*)d_in[13];
    const float* cW1 = (const float*)d_in[14];
    const float* cb1 = (const float*)d_in[15];
    const float* cg  = (const float*)d_in[16];
    const float* cbe = (const float*)d_in[17];
    const float* cW2 = (const float*)d_in[18];
    const float* cb2 = (const float*)d_in[19];
    const float* cW3 = (const float*)d_in[20];
    const float* cb3 = (const float*)d_in[21];
    const float* aq  = (const float*)d_in[22];
    const float* bq  = (const float*)d_in[23];
    const float* ak  = (const float*)d_in[24];
    const float* bk  = (const float*)d_in[25];
    const float* av  = (const float*)d_in[26];
    const float* bv  = (const float*)d_in[27];

    int* Tp = (int*)d_ws;
    unsigned short* q_sum  = (unsigned short*)((char*)d_ws + 16384);
    unsigned short* k_sum  = q_sum + (size_t)NROWS * EMB;
    unsigned short* v_mean = k_sum + (size_t)NROWS * EMB;
    float* attn = (float*)(v_mean + (size_t)NROWS * EMB);
    float* out  = (float*)d_out;

    gates_kernel<<<dim3(NROWS), dim3(128), 0, stream>>>(
        x, gW1, gb1, gg, gbe, gW2, gb2, gW3, gb3,
        cW1, cb1, cg, cbe, cW2, cb2, cW3, cb3, Tp);

    qkv_lif_kernel<<<dim3(EMB / 64, NROWS / 64, 3), dim3(256), 0, stream>>>(
        x, Wq, Wk, Wv, aq, bq, ak, bk, av, bv, Tp, q_sum, k_sum, v_mean);

    attn_mfma_kernel<<<dim3(SEQ / 64, 8, 4), dim3(256), 0, stream>>>(
        q_sum, k_sum, v_mean, attn);

    out_gemm_kernel<<<dim3(EMB / 64, NROWS / 64), dim3(256), 0, stream>>>(
        attn, Wo, bo, out);
}

// Round 4
// 391.217 us; speedup vs baseline: 3.5955x; 1.1977x over previous
//
#include <hip/hip_runtime.h>
#include <math.h>

// Problem constants (B=4, S=1024, E=512, H=8, D=64, T_MAX=20)
#define SEQ   1024
#define EMB   512
#define NROWS 4096   // B*S
#define LDP   72     // attn LDS row stride (bf16 elems)
#define GROWS 8      // gates rows per block

typedef __attribute__((ext_vector_type(8))) short short8;    // bf16 x8 MFMA frag
typedef __attribute__((ext_vector_type(4))) float float4v;   // f32 x4 MFMA acc

__device__ __forceinline__ float bf2f(unsigned short s) {
    union { float f; unsigned u; } x; x.u = ((unsigned)s) << 16; return x.f;
}
__device__ __forceinline__ unsigned short f2bf(float f) {
    union { float f; unsigned u; } x; x.f = f;
    unsigned r = x.u + 0x7fffu + ((x.u >> 16) & 1u);   // round-to-nearest-even
    return (unsigned short)(r >> 16);
}

// ---------------------------------------------------------------------------
// K0: gate + complexity MLPs -> T_i[4096]. 8 rows per block (256 threads).
// All math f64 to pin the ceil() discretization; score-formula constants
// written exactly as in the (passing) R2 kernel.
// ---------------------------------------------------------------------------
template<int H1, int H2>
__device__ __forceinline__ double gate_mlp_block(
    const double xs[GROWS][EMB], double h1[GROWS][128], double h2[GROWS][64],
    double* mu_s, double* var_s,
    const float* __restrict__ W1, const float* __restrict__ b1,
    const float* __restrict__ gam, const float* __restrict__ bet,
    const float* __restrict__ W2, const float* __restrict__ b2,
    const float* __restrict__ W3, const float* __restrict__ b3,
    int tid, int myrow)
{
    constexpr int RN1 = GROWS * H1 / 256;
    constexpr int RN2 = GROWS * H2 / 256;

    {   // h1 = x @ W1 + b1
        const int col = tid % H1;
        const int rb  = (tid / H1) * RN1;
        double acc[RN1];
        #pragma unroll
        for (int r = 0; r < RN1; ++r) acc[r] = (double)b1[col];
        for (int k = 0; k < EMB; ++k) {
            const double w = (double)W1[k * H1 + col];
            #pragma unroll
            for (int r = 0; r < RN1; ++r) acc[r] += w * xs[rb + r][k];
        }
        #pragma unroll
        for (int r = 0; r < RN1; ++r) h1[rb + r][col] = acc[r];
    }
    __syncthreads();

    {   // mean
        const int r = tid >> 5, l = tid & 31;
        double s = 0.0;
        for (int c = l; c < H1; c += 32) s += h1[r][c];
        #pragma unroll
        for (int off = 16; off >= 1; off >>= 1) s += __shfl_xor(s, off);
        if (l == 0) mu_s[r] = s / (double)H1;
    }
    __syncthreads();
    {   // var
        const int r = tid >> 5, l = tid & 31;
        const double mu = mu_s[r];
        double s = 0.0;
        for (int c = l; c < H1; c += 32) { const double d = h1[r][c] - mu; s += d * d; }
        #pragma unroll
        for (int off = 16; off >= 1; off >>= 1) s += __shfl_xor(s, off);
        if (l == 0) var_s[r] = s / (double)H1;
    }
    __syncthreads();
    // normalize + relu
    for (int idx = tid; idx < GROWS * H1; idx += 256) {
        const int r = idx / H1, cc = idx % H1;
        double hn = (h1[r][cc] - mu_s[r]) / sqrt(var_s[r] + 1e-5) * (double)gam[cc] + (double)bet[cc];
        h1[r][cc] = hn > 0.0 ? hn : 0.0;
    }
    __syncthreads();

    {   // h2 = relu(h1 @ W2 + b2)
        const int col = tid % H2;
        const int rb  = (tid / H2) * RN2;
        double acc[RN2];
        #pragma unroll
        for (int r = 0; r < RN2; ++r) acc[r] = (double)b2[col];
        for (int k = 0; k < H1; ++k) {
            const double w = (double)W2[k * H2 + col];
            #pragma unroll
            for (int r = 0; r < RN2; ++r) acc[r] += w * h1[rb + r][k];
        }
        #pragma unroll
        for (int r = 0; r < RN2; ++r) h2[rb + r][col] = acc[r] > 0.0 ? acc[r] : 0.0;
    }
    __syncthreads();

    {   // scalar = h2 @ W3 (sigmoid below)
        const int r = tid >> 5, l = tid & 31;
        double s = 0.0;
        for (int c = l; c < H2; c += 32) s += h2[r][c] * (double)W3[c];
        #pragma unroll
        for (int off = 16; off >= 1; off >>= 1) s += __shfl_xor(s, off);
        if (l == 0) mu_s[r] = s;   // reuse as scratch
    }
    __syncthreads();
    double ret = 0.0;
    if (myrow >= 0) {
        const double z = mu_s[myrow] + (double)b3[0];
        ret = 1.0 / (1.0 + exp(-z));
    }
    __syncthreads();
    return ret;
}

__global__ __launch_bounds__(256) void gates_kernel(
    const float* __restrict__ x,
    const float* __restrict__ gW1, const float* __restrict__ gb1,
    const float* __restrict__ gg,  const float* __restrict__ gbe,
    const float* __restrict__ gW2, const float* __restrict__ gb2,
    const float* __restrict__ gW3, const float* __restrict__ gb3,
    const float* __restrict__ cW1, const float* __restrict__ cb1,
    const float* __restrict__ cg,  const float* __restrict__ cbe,
    const float* __restrict__ cW2, const float* __restrict__ cb2,
    const float* __restrict__ cW3, const float* __restrict__ cb3,
    int* __restrict__ T_i)
{
    __shared__ double xs[GROWS][EMB];     // 32 KB
    __shared__ double h1[GROWS][128];     // 8 KB
    __shared__ double h2[GROWS][64];      // 4 KB
    __shared__ double mu_s[GROWS], var_s[GROWS];

    const int row0 = blockIdx.x * GROWS;
    const int tid = threadIdx.x;

    for (int idx = tid; idx < GROWS * EMB; idx += 256) {
        const int r = idx >> 9, cc = idx & 511;
        xs[r][cc] = (double)x[(size_t)(row0 + r) * EMB + cc];
    }
    __syncthreads();

    const int myrow = (tid < GROWS) ? tid : -1;
    const double g0 = gate_mlp_block<128, 64>(xs, h1, h2, mu_s, var_s,
                                              gW1, gb1, gg, gbe, gW2, gb2, gW3, gb3, tid, myrow);
    const double c0 = gate_mlp_block<64, 32>(xs, h1, h2, mu_s, var_s,
                                             cW1, cb1, cg, cbe, cW2, cb2, cW3, cb3, tid, myrow);

    if (tid < GROWS) {
        const int row = row0 + tid;
        const int s = row & (SEQ - 1);
        const double step = (1.2 - 0.8) / (double)(SEQ - 1);   // np.linspace step
        const double pos  = (double)s * step + 0.8;
        const double score = ((1.0 - 0.3) * g0 + 0.3 * c0) * pos;
        double t = ceil(score * 20.0);
        t = t < 1.0 ? 1.0 : (t > 20.0 ? 20.0 : t);
        T_i[row] = (int)t;
    }
}

// ---------------------------------------------------------------------------
// K1: QKV GEMM, f64 on the VALU (verified-correct semantics from R2) but
// restructured: f32->f64 convert once at LDS staging, 128x64 tile, 8x4 f64
// acc per thread (32 FMA per 10 LDS reads; a-reads are 16-lane broadcasts).
// LIF epilogue in f64, bf16 out.
// ---------------------------------------------------------------------------
__global__ __launch_bounds__(256) void qkv_lif_kernel(
    const float* __restrict__ x,
    const float* __restrict__ Wq, const float* __restrict__ Wk, const float* __restrict__ Wv,
    const float* __restrict__ aq, const float* __restrict__ bq,
    const float* __restrict__ akp, const float* __restrict__ bkp,
    const float* __restrict__ av, const float* __restrict__ bv,
    const int* __restrict__ T_i,
    unsigned short* __restrict__ q_sum, unsigned short* __restrict__ k_sum,
    unsigned short* __restrict__ v_mean)
{
    const int z = blockIdx.z;
    const float* __restrict__ W = (z == 0) ? Wq : (z == 1) ? Wk : Wv;
    unsigned short* __restrict__ out = (z == 0) ? q_sum : (z == 1) ? k_sum : v_mean;
    const double alpha = (double)((z == 0) ? aq : (z == 1) ? akp : av)[0];
    const double beta  = (double)((z == 0) ? bq : (z == 1) ? bkp : bv)[0];

    __shared__ double As[128][18];   // [m][k], 18.4 KB (pad 18)
    __shared__ double Bs[16][66];    // [k][n], 8.4 KB (pad 66)

    const int tid = threadIdx.x;
    const int tx = tid & 15, ty = tid >> 4;            // col grp 0..15, row grp 0..15
    const int row0 = blockIdx.y * 128, col0 = blockIdx.x * 64;

    double acc[8][4];
    #pragma unroll
    for (int i = 0; i < 8; ++i)
        #pragma unroll
        for (int j = 0; j < 4; ++j) acc[i][j] = 0.0;

    const int am  = tid >> 1, ak8 = (tid & 1) * 8;     // A staging: row, 8-float chunk
    const int bkr = tid >> 4, bn4 = (tid & 15) * 4;    // B staging: k-row, 4-float chunk

    for (int k0 = 0; k0 < EMB; k0 += 16) {
        const float4 a40 = *(const float4*)&x[(size_t)(row0 + am) * EMB + k0 + ak8];
        const float4 a41 = *(const float4*)&x[(size_t)(row0 + am) * EMB + k0 + ak8 + 4];
        As[am][ak8 + 0] = (double)a40.x; As[am][ak8 + 1] = (double)a40.y;
        As[am][ak8 + 2] = (double)a40.z; As[am][ak8 + 3] = (double)a40.w;
        As[am][ak8 + 4] = (double)a41.x; As[am][ak8 + 5] = (double)a41.y;
        As[am][ak8 + 6] = (double)a41.z; As[am][ak8 + 7] = (double)a41.w;
        const float4 b4 = *(const float4*)&W[(size_t)(k0 + bkr) * EMB + col0 + bn4];
        Bs[bkr][bn4 + 0] = (double)b4.x; Bs[bkr][bn4 + 1] = (double)b4.y;
        Bs[bkr][bn4 + 2] = (double)b4.z; Bs[bkr][bn4 + 3] = (double)b4.w;
        __syncthreads();
        #pragma unroll
        for (int kk = 0; kk < 16; ++kk) {
            double bb[4];
            #pragma unroll
            for (int j = 0; j < 4; ++j) bb[j] = Bs[kk][tx * 4 + j];
            #pragma unroll
            for (int i = 0; i < 8; ++i) {
                const double aa = As[ty * 8 + i][kk];
                #pragma unroll
                for (int j = 0; j < 4; ++j) acc[i][j] += aa * bb[j];
            }
        }
        __syncthreads();
    }

    // LIF epilogue (f64), write bf16
    #pragma unroll
    for (int i = 0; i < 8; ++i) {
        const int gm = row0 + ty * 8 + i;
        const int T = T_i[gm];
        ushort4 pack;
        unsigned short* pk = (unsigned short*)&pack;
        #pragma unroll
        for (int j = 0; j < 4; ++j) {
            const double xv = acc[i][j];
            double cur = 0.0, vm = 0.0, spikes = 0.0;
            for (int t = 0; t < T; ++t) {
                cur = alpha * cur + xv;
                vm  = beta * vm + cur;
                if (vm >= 1.0) { spikes += 1.0; vm = 0.0; }
            }
            if (z == 2) spikes = spikes / 20.0;
            pk[j] = f2bf((float)spikes);
        }
        *(ushort4*)&out[(size_t)gm * EMB + col0 + tx * 4] = pack;
    }
}

// ---------------------------------------------------------------------------
// K2: fused flash-style MFMA attention; epilogue emits bf16.
// ---------------------------------------------------------------------------
__global__ __launch_bounds__(256) void attn_mfma_kernel(
    const unsigned short* __restrict__ q, const unsigned short* __restrict__ k,
    const unsigned short* __restrict__ v, unsigned short* __restrict__ attn_bf)
{
    __shared__ __align__(16) short Ks[64 * LDP];
    __shared__ __align__(16) short Pt[64 * LDP];
    __shared__ __align__(16) short Vt[64 * LDP];

    const int b = blockIdx.z, h = blockIdx.y;
    const int i0 = blockIdx.x * 64;
    const int tid  = threadIdx.x;
    const int wave = tid >> 6, lane = tid & 63;
    const int quad = lane >> 4, c = lane & 15;

    const unsigned short* Qb = q + ((size_t)b * SEQ + i0) * EMB + h * 64;
    const unsigned short* Kb = k + (size_t)b * SEQ * EMB + h * 64;
    const unsigned short* Vb = v + (size_t)b * SEQ * EMB + h * 64;

    short8 qf[2];
    {
        const int qrow = wave * 16 + c;
        #pragma unroll
        for (int ks = 0; ks < 2; ++ks) {
            short8 raw = *(const short8*)(Qb + (size_t)qrow * EMB + ks * 32 + quad * 8);
            short8 sc8;
            #pragma unroll
            for (int j = 0; j < 8; ++j)
                sc8[j] = (short)f2bf(bf2f((unsigned short)raw[j]) * 0.125f);
            qf[ks] = sc8;
        }
    }

    float m_r[4], l_r[4];
    float4v o[4];
    #pragma unroll
    for (int r = 0; r < 4; ++r) { m_r[r] = -1e30f; l_r[r] = 0.f; }
    #pragma unroll
    for (int nb = 0; nb < 4; ++nb)
        #pragma unroll
        for (int r = 0; r < 4; ++r) o[nb][r] = 0.f;

    for (int jt = 0; jt < SEQ / 64; ++jt) {
        #pragma unroll
        for (int it = 0; it < 2; ++it) {
            const int idx = it * 256 + tid;
            const int row = idx >> 3, ch = idx & 7;
            short8 val = *(const short8*)(Kb + (size_t)(jt * 64 + row) * EMB + ch * 8);
            *(short8*)&Ks[row * LDP + ch * 8] = val;
        }
        __syncthreads();

        float sc[4][4];
        #pragma unroll
        for (int nb = 0; nb < 4; ++nb) {
            float4v acc = {0.f, 0.f, 0.f, 0.f};
            #pragma unroll
            for (int ks = 0; ks < 2; ++ks) {
                short8 bfrag = *(const short8*)&Ks[(nb * 16 + c) * LDP + ks * 32 + quad * 8];
                acc = __builtin_amdgcn_mfma_f32_16x16x32_bf16(qf[ks], bfrag, acc, 0, 0, 0);
            }
            #pragma unroll
            for (int r = 0; r < 4; ++r) sc[nb][r] = acc[r];
        }

        float mnew[4], alpha[4];
        #pragma unroll
        for (int r = 0; r < 4; ++r) {
            float mx = fmaxf(fmaxf(sc[0][r], sc[1][r]), fmaxf(sc[2][r], sc[3][r]));
            #pragma unroll
            for (int off = 8; off >= 1; off >>= 1) mx = fmaxf(mx, __shfl_xor(mx, off));
            mnew[r]  = fmaxf(m_r[r], mx);
            alpha[r] = __expf(m_r[r] - mnew[r]);
            m_r[r]   = mnew[r];
        }
        float psum[4] = {0.f, 0.f, 0.f, 0.f};
        #pragma unroll
        for (int nb = 0; nb < 4; ++nb)
            #pragma unroll
            for (int r = 0; r < 4; ++r) {
                float p = __expf(sc[nb][r] - mnew[r]);
                psum[r] += p;
                Pt[(wave * 16 + quad * 4 + r) * LDP + nb * 16 + c] = (short)f2bf(p);
            }
        #pragma unroll
        for (int r = 0; r < 4; ++r) {
            float s = psum[r];
            #pragma unroll
            for (int off = 8; off >= 1; off >>= 1) s += __shfl_xor(s, off);
            l_r[r] = l_r[r] * alpha[r] + s;
            #pragma unroll
            for (int nb = 0; nb < 4; ++nb) o[nb][r] *= alpha[r];
        }

        {
            const int m = tid & 7, rp = tid >> 3;
            const int r = rp * 2;
            short8 v0 = *(const short8*)(Vb + (size_t)(jt * 64 + r) * EMB + m * 8);
            short8 v1 = *(const short8*)(Vb + (size_t)(jt * 64 + r + 1) * EMB + m * 8);
            const int rch = r >> 3, rlow = r & 7;
            #pragma unroll
            for (int i = 0; i < 8; ++i) {
                const int d = m * 8 + i;
                const int col = ((rch ^ m) << 3) + rlow;
                *(int*)&Vt[d * LDP + col] =
                    (int)((unsigned)(unsigned short)v0[i] |
                          ((unsigned)(unsigned short)v1[i] << 16));
            }
        }
        __syncthreads();

        short8 pf[2];
        #pragma unroll
        for (int ks = 0; ks < 2; ++ks)
            pf[ks] = *(const short8*)&Pt[(wave * 16 + c) * LDP + ks * 32 + quad * 8];
        #pragma unroll
        for (int nb = 0; nb < 4; ++nb) {
            float4v acc = o[nb];
            #pragma unroll
            for (int ks = 0; ks < 2; ++ks) {
                const int d = nb * 16 + c;
                const int kch = ks * 4 + quad;
                const int col = ((kch ^ (d >> 3)) << 3);
                short8 vfrag = *(const short8*)&Vt[d * LDP + col];
                acc = __builtin_amdgcn_mfma_f32_16x16x32_bf16(pf[ks], vfrag, acc, 0, 0, 0);
            }
            o[nb] = acc;
        }
    }

    #pragma unroll
    for (int r = 0; r < 4; ++r) {
        const float inv = 1.0f / l_r[r];
        const int row = i0 + wave * 16 + quad * 4 + r;
        #pragma unroll
        for (int nb = 0; nb < 4; ++nb)
            attn_bf[((size_t)b * SEQ + row) * EMB + h * 64 + nb * 16 + c] =
                f2bf(o[nb][r] * inv);
    }
}

// ---------------------------------------------------------------------------
// K3a: Wo^T bf16 prep (64x64 LDS transpose tiles).
// ---------------------------------------------------------------------------
__global__ __launch_bounds__(256) void wot_prep(
    const float* __restrict__ Wo, unsigned short* __restrict__ BT)
{
    __shared__ unsigned short Ws[64][72];
    const int k0 = blockIdx.y * 64, n0 = blockIdx.x * 64;
    const int t = threadIdx.x;
    #pragma unroll
    for (int it = 0; it < 4; ++it) {
        const int idx = it * 256 + t;
        const int r = idx >> 4, c4 = (idx & 15) * 4;
        const float4 w4 = *(const float4*)&Wo[(size_t)(k0 + r) * EMB + n0 + c4];
        Ws[r][c4 + 0] = f2bf(w4.x); Ws[r][c4 + 1] = f2bf(w4.y);
        Ws[r][c4 + 2] = f2bf(w4.z); Ws[r][c4 + 3] = f2bf(w4.w);
    }
    __syncthreads();
    #pragma unroll
    for (int it = 0; it < 2; ++it) {
        const int idx = it * 256 + t;
        const int n = idx >> 3, k8 = (idx & 7) * 8;
        short8 pack;
        #pragma unroll
        for (int j = 0; j < 8; ++j) pack[j] = (short)Ws[k8 + j][n];
        *(short8*)&BT[(size_t)(n0 + n) * EMB + k0 + k8] = pack;
    }
}

// ---------------------------------------------------------------------------
// K3b: out = attn_bf @ Wo + bo via bf16 MFMA, frags direct from global (L2).
// ---------------------------------------------------------------------------
__global__ __launch_bounds__(256) void out_gemm_kernel(
    const unsigned short* __restrict__ A,   // [4096][512] bf16
    const unsigned short* __restrict__ BT,  // [512][512] bf16, [n][k]
    const float* __restrict__ bias, float* __restrict__ out)
{
    const int tid  = threadIdx.x;
    const int lane = tid & 63, wave = tid >> 6;
    const int qd = lane >> 4, c = lane & 15;
    const int wm = (wave & 1) * 32, wn = (wave >> 1) * 32;
    const int row0 = blockIdx.y * 64, col0 = blockIdx.x * 64;

    float4v acc[2][2];
    #pragma unroll
    for (int i = 0; i < 2; ++i)
        #pragma unroll
        for (int j = 0; j < 2; ++j)
            acc[i][j] = (float4v){0.f, 0.f, 0.f, 0.f};

    for (int k0 = 0; k0 < EMB; k0 += 32) {
        short8 af[2], bf[2];
        #pragma unroll
        for (int i = 0; i < 2; ++i)
            af[i] = *(const short8*)&A[(size_t)(row0 + wm + i * 16 + c) * EMB + k0 + qd * 8];
        #pragma unroll
        for (int j = 0; j < 2; ++j)
            bf[j] = *(const short8*)&BT[(size_t)(col0 + wn + j * 16 + c) * EMB + k0 + qd * 8];
        #pragma unroll
        for (int i = 0; i < 2; ++i)
            #pragma unroll
            for (int j = 0; j < 2; ++j)
                acc[i][j] = __builtin_amdgcn_mfma_f32_16x16x32_bf16(af[i], bf[j], acc[i][j], 0, 0, 0);
    }

    #pragma unroll
    for (int i = 0; i < 2; ++i)
        #pragma unroll
        for (int r = 0; r < 4; ++r) {
            const int gm = row0 + wm + i * 16 + qd * 4 + r;
            #pragma unroll
            for (int j = 0; j < 2; ++j) {
                const int gn = col0 + wn + j * 16 + c;
                out[(size_t)gm * EMB + gn] = acc[i][j][r] + bias[gn];
            }
        }
}

// ---------------------------------------------------------------------------
extern "C" void kernel_launch(void* const* d_in, const int* in_sizes, int n_in,
                              void* d_out, int out_size, void* d_ws, size_t ws_size,
                              hipStream_t stream)
{
    const float* x   = (const float*)d_in[0];
    const float* Wq  = (const float*)d_in[1];
    const float* Wk  = (const float*)d_in[2];
    const float* Wv  = (const float*)d_in[3];
    const float* Wo  = (const float*)d_in[4];
    const float* bo  = (const float*)d_in[5];
    const float* gW1 = (const float*)d_in[6];
    const float* gb1 = (const float*)d_in[7];
    const float* gg  = (const float*)d_in[8];
    const float* gbe = (const float*)d_in[9];
    const float* gW2 = (const float*)d_in[10];
    const float* gb2 = (const float*)d_in[11];
    const float* gW3 = (const float*)d_in[12];
    const float* gb3 = (const float*)d_in[13];
    const float* cW1 = (const float*)d_in[14];
    const float* cb1 = (const float*)d_in[15];
    const float* cg  = (const float*)d_in[16];
    const float* cbe = (const float*)d_in[17];
    const float* cW2 = (const float*)d_in[18];
    const float* cb2 = (const float*)d_in[19];
    const float* cW3 = (const float*)d_in[20];
    const float* cb3 = (const float*)d_in[21];
    const float* aq  = (const float*)d_in[22];
    const float* bq  = (const float*)d_in[23];
    const float* ak  = (const float*)d_in[24];
    const float* bk  = (const float*)d_in[25];
    const float* av  = (const float*)d_in[26];
    const float* bv  = (const float*)d_in[27];

    int* Tp = (int*)d_ws;
    unsigned short* q_sum   = (unsigned short*)((char*)d_ws + 16384);
    unsigned short* k_sum   = q_sum   + (size_t)NROWS * EMB;
    unsigned short* v_mean  = k_sum   + (size_t)NROWS * EMB;
    unsigned short* attn_bf = v_mean  + (size_t)NROWS * EMB;
    unsigned short* WoT     = attn_bf + (size_t)NROWS * EMB;
    float* out = (float*)d_out;

    gates_kernel<<<dim3(NROWS / GROWS), dim3(256), 0, stream>>>(
        x, gW1, gb1, gg, gbe, gW2, gb2, gW3, gb3,
        cW1, cb1, cg, cbe, cW2, cb2, cW3, cb3, Tp);

    qkv_lif_kernel<<<dim3(EMB / 64, NROWS / 128, 3), dim3(256), 0, stream>>>(
        x, Wq, Wk, Wv, aq, bq, ak, bk, av, bv, Tp, q_sum, k_sum, v_mean);

    wot_prep<<<dim3(EMB / 64, EMB / 64), dim3(256), 0, stream>>>(Wo, WoT);

    attn_mfma_kernel<<<dim3(SEQ / 64, 8, 4), dim3(256), 0, stream>>>(
        q_sum, k_sum, v_mean, attn_bf);

    out_gemm_kernel<<<dim3(EMB / 64, NROWS / 64), dim3(256), 0, stream>>>(
        attn_bf, WoT, bo, out);
}

// Round 6
// 332.871 us; speedup vs baseline: 4.2257x; 1.1753x over previous
//
#include <hip/hip_runtime.h>
#include <math.h>

// Problem constants (B=4, S=1024, E=512, H=8, D=64, T_MAX=20)
#define SEQ   1024
#define EMB   512
#define NROWS 4096   // B*S
#define LDP   72     // attn LDS row stride (bf16 elems)
#define GROWS 8      // gates rows per block

typedef __attribute__((ext_vector_type(8))) short short8;    // bf16 x8 MFMA frag
typedef __attribute__((ext_vector_type(4))) float float4v;   // f32 x4 MFMA acc

__device__ __forceinline__ float bf2f(unsigned short s) {
    union { float f; unsigned u; } x; x.u = ((unsigned)s) << 16; return x.f;
}
__device__ __forceinline__ unsigned short f2bf(float f) {
    union { float f; unsigned u; } x; x.f = f;
    unsigned r = x.u + 0x7fffu + ((x.u >> 16) & 1u);   // round-to-nearest-even
    return (unsigned short)(r >> 16);
}

// ---------------------------------------------------------------------------
// K0: gate + complexity MLPs -> T_i[4096]. 8 rows per block (256 threads).
// All math f64 to pin the ceil() discretization (passing R2/R4 version).
// ---------------------------------------------------------------------------
template<int H1, int H2>
__device__ __forceinline__ double gate_mlp_block(
    const double xs[GROWS][EMB], double h1[GROWS][128], double h2[GROWS][64],
    double* mu_s, double* var_s,
    const float* __restrict__ W1, const float* __restrict__ b1,
    const float* __restrict__ gam, const float* __restrict__ bet,
    const float* __restrict__ W2, const float* __restrict__ b2,
    const float* __restrict__ W3, const float* __restrict__ b3,
    int tid, int myrow)
{
    constexpr int RN1 = GROWS * H1 / 256;
    constexpr int RN2 = GROWS * H2 / 256;

    {   // h1 = x @ W1 + b1
        const int col = tid % H1;
        const int rb  = (tid / H1) * RN1;
        double acc[RN1];
        #pragma unroll
        for (int r = 0; r < RN1; ++r) acc[r] = (double)b1[col];
        for (int k = 0; k < EMB; ++k) {
            const double w = (double)W1[k * H1 + col];
            #pragma unroll
            for (int r = 0; r < RN1; ++r) acc[r] += w * xs[rb + r][k];
        }
        #pragma unroll
        for (int r = 0; r < RN1; ++r) h1[rb + r][col] = acc[r];
    }
    __syncthreads();

    {   // mean
        const int r = tid >> 5, l = tid & 31;
        double s = 0.0;
        for (int c = l; c < H1; c += 32) s += h1[r][c];
        #pragma unroll
        for (int off = 16; off >= 1; off >>= 1) s += __shfl_xor(s, off);
        if (l == 0) mu_s[r] = s / (double)H1;
    }
    __syncthreads();
    {   // var
        const int r = tid >> 5, l = tid & 31;
        const double mu = mu_s[r];
        double s = 0.0;
        for (int c = l; c < H1; c += 32) { const double d = h1[r][c] - mu; s += d * d; }
        #pragma unroll
        for (int off = 16; off >= 1; off >>= 1) s += __shfl_xor(s, off);
        if (l == 0) var_s[r] = s / (double)H1;
    }
    __syncthreads();
    // normalize + relu
    for (int idx = tid; idx < GROWS * H1; idx += 256) {
        const int r = idx / H1, cc = idx % H1;
        double hn = (h1[r][cc] - mu_s[r]) / sqrt(var_s[r] + 1e-5) * (double)gam[cc] + (double)bet[cc];
        h1[r][cc] = hn > 0.0 ? hn : 0.0;
    }
    __syncthreads();

    {   // h2 = relu(h1 @ W2 + b2)
        const int col = tid % H2;
        const int rb  = (tid / H2) * RN2;
        double acc[RN2];
        #pragma unroll
        for (int r = 0; r < RN2; ++r) acc[r] = (double)b2[col];
        for (int k = 0; k < H1; ++k) {
            const double w = (double)W2[k * H2 + col];
            #pragma unroll
            for (int r = 0; r < RN2; ++r) acc[r] += w * h1[rb + r][k];
        }
        #pragma unroll
        for (int r = 0; r < RN2; ++r) h2[rb + r][col] = acc[r] > 0.0 ? acc[r] : 0.0;
    }
    __syncthreads();

    {   // scalar = h2 @ W3 (sigmoid below)
        const int r = tid >> 5, l = tid & 31;
        double s = 0.0;
        for (int c = l; c < H2; c += 32) s += h2[r][c] * (double)W3[c];
        #pragma unroll
        for (int off = 16; off >= 1; off >>= 1) s += __shfl_xor(s, off);
        if (l == 0) mu_s[r] = s;   // reuse as scratch
    }
    __syncthreads();
    double ret = 0.0;
    if (myrow >= 0) {
        const double z = mu_s[myrow] + (double)b3[0];
        ret = 1.0 / (1.0 + exp(-z));
    }
    __syncthreads();
    return ret;
}

__global__ __launch_bounds__(256) void gates_kernel(
    const float* __restrict__ x,
    const float* __restrict__ gW1, const float* __restrict__ gb1,
    const float* __restrict__ gg,  const float* __restrict__ gbe,
    const float* __restrict__ gW2, const float* __restrict__ gb2,
    const float* __restrict__ gW3, const float* __restrict__ gb3,
    const float* __restrict__ cW1, const float* __restrict__ cb1,
    const float* __restrict__ cg,  const float* __restrict__ cbe,
    const float* __restrict__ cW2, const float* __restrict__ cb2,
    const float* __restrict__ cW3, const float* __restrict__ cb3,
    int* __restrict__ T_i)
{
    __shared__ double xs[GROWS][EMB];     // 32 KB
    __shared__ double h1[GROWS][128];     // 8 KB
    __shared__ double h2[GROWS][64];      // 4 KB
    __shared__ double mu_s[GROWS], var_s[GROWS];

    const int row0 = blockIdx.x * GROWS;
    const int tid = threadIdx.x;

    for (int idx = tid; idx < GROWS * EMB; idx += 256) {
        const int r = idx >> 9, cc = idx & 511;
        xs[r][cc] = (double)x[(size_t)(row0 + r) * EMB + cc];
    }
    __syncthreads();

    const int myrow = (tid < GROWS) ? tid : -1;
    const double g0 = gate_mlp_block<128, 64>(xs, h1, h2, mu_s, var_s,
                                              gW1, gb1, gg, gbe, gW2, gb2, gW3, gb3, tid, myrow);
    const double c0 = gate_mlp_block<64, 32>(xs, h1, h2, mu_s, var_s,
                                             cW1, cb1, cg, cbe, cW2, cb2, cW3, cb3, tid, myrow);

    if (tid < GROWS) {
        const int row = row0 + tid;
        const int s = row & (SEQ - 1);
        const double step = (1.2 - 0.8) / (double)(SEQ - 1);   // np.linspace step
        const double pos  = (double)s * step + 0.8;
        const double score = ((1.0 - 0.3) * g0 + 0.3 * c0) * pos;
        double t = ceil(score * 20.0);
        t = t < 1.0 ? 1.0 : (t > 20.0 ? 20.0 : t);
        T_i[row] = (int)t;
    }
}

// ---------------------------------------------------------------------------
// K1: QKV GEMM in f32 on the VALU (error-budget experiment: flips vs the np
// reference are dominated by the ref's own f32 noise — R4 analysis).
// A staged TRANSPOSED in LDS (Ast[k][m]): per-kk fragment reads are two
// ds_read_b128 broadcast across 16-lane groups (banks 0/8/16/24 — no
// conflicts). 128x64 tile, 8x4 acc/thread. LIF epilogue f64, bf16 out.
// Inner loop is pure float4 component math (no local arrays).
// ---------------------------------------------------------------------------
__global__ __launch_bounds__(256) void qkv_lif_kernel(
    const float* __restrict__ x,
    const float* __restrict__ Wq, const float* __restrict__ Wk, const float* __restrict__ Wv,
    const float* __restrict__ aq, const float* __restrict__ bq,
    const float* __restrict__ akp, const float* __restrict__ bkp,
    const float* __restrict__ av, const float* __restrict__ bv,
    const int* __restrict__ T_i,
    unsigned short* __restrict__ q_sum, unsigned short* __restrict__ k_sum,
    unsigned short* __restrict__ v_mean)
{
    const int z = blockIdx.z;
    const float* __restrict__ W = (z == 0) ? Wq : (z == 1) ? Wk : Wv;
    unsigned short* __restrict__ out = (z == 0) ? q_sum : (z == 1) ? k_sum : v_mean;
    const double alpha = (double)((z == 0) ? aq : (z == 1) ? akp : av)[0];
    const double beta  = (double)((z == 0) ? bq : (z == 1) ? bkp : bv)[0];

    __shared__ __align__(16) float Ast[16][132];  // [k][m], 8.4 KB
    __shared__ __align__(16) float Bs[16][68];    // [k][n], 4.4 KB

    const int tid = threadIdx.x;
    const int tx = tid & 15, ty = tid >> 4;            // col grp 0..15, row grp 0..15
    const int row0 = blockIdx.y * 128, col0 = blockIdx.x * 64;

    float4 acc0[8], acc1[8];   // acc0[i] = cols {0,1,2,3} of row i... (x,y,z,w = j)
    #pragma unroll
    for (int i = 0; i < 8; ++i) {
        acc0[i] = (float4){0.f, 0.f, 0.f, 0.f};
        acc1[i] = (float4){0.f, 0.f, 0.f, 0.f};   // unused cols guard (kept zero)
    }

    const int am  = tid >> 1, ak8 = (tid & 1) * 8;     // A staging: row, 8-float k-chunk
    const int bkr = tid >> 4, bn4 = (tid & 15) * 4;    // B staging: k-row, 4-float n-chunk

    for (int k0 = 0; k0 < EMB; k0 += 16) {
        const float4 a40 = *(const float4*)&x[(size_t)(row0 + am) * EMB + k0 + ak8];
        const float4 a41 = *(const float4*)&x[(size_t)(row0 + am) * EMB + k0 + ak8 + 4];
        Ast[ak8 + 0][am] = a40.x; Ast[ak8 + 1][am] = a40.y;
        Ast[ak8 + 2][am] = a40.z; Ast[ak8 + 3][am] = a40.w;
        Ast[ak8 + 4][am] = a41.x; Ast[ak8 + 5][am] = a41.y;
        Ast[ak8 + 6][am] = a41.z; Ast[ak8 + 7][am] = a41.w;
        const float4 b4 = *(const float4*)&W[(size_t)(k0 + bkr) * EMB + col0 + bn4];
        *(float4*)&Bs[bkr][bn4] = b4;
        __syncthreads();
        #pragma unroll
        for (int kk = 0; kk < 16; ++kk) {
            const float4 a0 = *(const float4*)&Ast[kk][ty * 8];
            const float4 a1 = *(const float4*)&Ast[kk][ty * 8 + 4];
            const float4 bb = *(const float4*)&Bs[kk][tx * 4];
            acc0[0].x += a0.x * bb.x; acc0[0].y += a0.x * bb.y; acc0[0].z += a0.x * bb.z; acc0[0].w += a0.x * bb.w;
            acc0[1].x += a0.y * bb.x; acc0[1].y += a0.y * bb.y; acc0[1].z += a0.y * bb.z; acc0[1].w += a0.y * bb.w;
            acc0[2].x += a0.z * bb.x; acc0[2].y += a0.z * bb.y; acc0[2].z += a0.z * bb.z; acc0[2].w += a0.z * bb.w;
            acc0[3].x += a0.w * bb.x; acc0[3].y += a0.w * bb.y; acc0[3].z += a0.w * bb.z; acc0[3].w += a0.w * bb.w;
            acc0[4].x += a1.x * bb.x; acc0[4].y += a1.x * bb.y; acc0[4].z += a1.x * bb.z; acc0[4].w += a1.x * bb.w;
            acc0[5].x += a1.y * bb.x; acc0[5].y += a1.y * bb.y; acc0[5].z += a1.y * bb.z; acc0[5].w += a1.y * bb.w;
            acc0[6].x += a1.z * bb.x; acc0[6].y += a1.z * bb.y; acc0[6].z += a1.z * bb.z; acc0[6].w += a1.z * bb.w;
            acc0[7].x += a1.w * bb.x; acc0[7].y += a1.w * bb.y; acc0[7].z += a1.w * bb.z; acc0[7].w += a1.w * bb.w;
        }
        __syncthreads();
    }

    // LIF epilogue (f64), write bf16
    #pragma unroll
    for (int i = 0; i < 8; ++i) {
        const int gm = row0 + ty * 8 + i;
        const int T = T_i[gm];
        float vals[4] = {acc0[i].x, acc0[i].y, acc0[i].z, acc0[i].w};
        ushort4 pack;
        unsigned short* pk = (unsigned short*)&pack;
        #pragma unroll
        for (int j = 0; j < 4; ++j) {
            const double xv = (double)vals[j];
            double cur = 0.0, vm = 0.0, spikes = 0.0;
            for (int t = 0; t < T; ++t) {
                cur = alpha * cur + xv;
                vm  = beta * vm + cur;
                if (vm >= 1.0) { spikes += 1.0; vm = 0.0; }
            }
            if (z == 2) spikes = spikes / 20.0;
            pk[j] = f2bf((float)spikes);
        }
        *(ushort4*)&out[(size_t)gm * EMB + col0 + tx * 4] = pack;
    }
}

// ---------------------------------------------------------------------------
// K2: fused flash-style MFMA attention; epilogue emits bf16.
// ---------------------------------------------------------------------------
__global__ __launch_bounds__(256) void attn_mfma_kernel(
    const unsigned short* __restrict__ q, const unsigned short* __restrict__ k,
    const unsigned short* __restrict__ v, unsigned short* __restrict__ attn_bf)
{
    __shared__ __align__(16) short Ks[64 * LDP];
    __shared__ __align__(16) short Pt[64 * LDP];
    __shared__ __align__(16) short Vt[64 * LDP];

    const int b = blockIdx.z, h = blockIdx.y;
    const int i0 = blockIdx.x * 64;
    const int tid  = threadIdx.x;
    const int wave = tid >> 6, lane = tid & 63;
    const int quad = lane >> 4, c = lane & 15;

    const unsigned short* Qb = q + ((size_t)b * SEQ + i0) * EMB + h * 64;
    const unsigned short* Kb = k + (size_t)b * SEQ * EMB + h * 64;
    const unsigned short* Vb = v + (size_t)b * SEQ * EMB + h * 64;

    short8 qf[2];
    {
        const int qrow = wave * 16 + c;
        #pragma unroll
        for (int ks = 0; ks < 2; ++ks) {
            short8 raw = *(const short8*)(Qb + (size_t)qrow * EMB + ks * 32 + quad * 8);
            short8 sc8;
            #pragma unroll
            for (int j = 0; j < 8; ++j)
                sc8[j] = (short)f2bf(bf2f((unsigned short)raw[j]) * 0.125f);
            qf[ks] = sc8;
        }
    }

    float m_r[4], l_r[4];
    float4v o[4];
    #pragma unroll
    for (int r = 0; r < 4; ++r) { m_r[r] = -1e30f; l_r[r] = 0.f; }
    #pragma unroll
    for (int nb = 0; nb < 4; ++nb)
        #pragma unroll
        for (int r = 0; r < 4; ++r) o[nb][r] = 0.f;

    for (int jt = 0; jt < SEQ / 64; ++jt) {
        #pragma unroll
        for (int it = 0; it < 2; ++it) {
            const int idx = it * 256 + tid;
            const int row = idx >> 3, ch = idx & 7;
            short8 val = *(const short8*)(Kb + (size_t)(jt * 64 + row) * EMB + ch * 8);
            *(short8*)&Ks[row * LDP + ch * 8] = val;
        }
        __syncthreads();

        float sc[4][4];
        #pragma unroll
        for (int nb = 0; nb < 4; ++nb) {
            float4v acc = {0.f, 0.f, 0.f, 0.f};
            #pragma unroll
            for (int ks = 0; ks < 2; ++ks) {
                short8 bfrag = *(const short8*)&Ks[(nb * 16 + c) * LDP + ks * 32 + quad * 8];
                acc = __builtin_amdgcn_mfma_f32_16x16x32_bf16(qf[ks], bfrag, acc, 0, 0, 0);
            }
            #pragma unroll
            for (int r = 0; r < 4; ++r) sc[nb][r] = acc[r];
        }

        float mnew[4], alpha[4];
        #pragma unroll
        for (int r = 0; r < 4; ++r) {
            float mx = fmaxf(fmaxf(sc[0][r], sc[1][r]), fmaxf(sc[2][r], sc[3][r]));
            #pragma unroll
            for (int off = 8; off >= 1; off >>= 1) mx = fmaxf(mx, __shfl_xor(mx, off));
            mnew[r]  = fmaxf(m_r[r], mx);
            alpha[r] = __expf(m_r[r] - mnew[r]);
            m_r[r]   = mnew[r];
        }
        float psum[4] = {0.f, 0.f, 0.f, 0.f};
        #pragma unroll
        for (int nb = 0; nb < 4; ++nb)
            #pragma unroll
            for (int r = 0; r < 4; ++r) {
                float p = __expf(sc[nb][r] - mnew[r]);
                psum[r] += p;
                Pt[(wave * 16 + quad * 4 + r) * LDP + nb * 16 + c] = (short)f2bf(p);
            }
        #pragma unroll
        for (int r = 0; r < 4; ++r) {
            float s = psum[r];
            #pragma unroll
            for (int off = 8; off >= 1; off >>= 1) s += __shfl_xor(s, off);
            l_r[r] = l_r[r] * alpha[r] + s;
            #pragma unroll
            for (int nb = 0; nb < 4; ++nb) o[nb][r] *= alpha[r];
        }

        {
            const int m = tid & 7, rp = tid >> 3;
            const int r = rp * 2;
            short8 v0 = *(const short8*)(Vb + (size_t)(jt * 64 + r) * EMB + m * 8);
            short8 v1 = *(const short8*)(Vb + (size_t)(jt * 64 + r + 1) * EMB + m * 8);
            const int rch = r >> 3, rlow = r & 7;
            #pragma unroll
            for (int i = 0; i < 8; ++i) {
                const int d = m * 8 + i;
                const int col = ((rch ^ m) << 3) + rlow;
                *(int*)&Vt[d * LDP + col] =
                    (int)((unsigned)(unsigned short)v0[i] |
                          ((unsigned)(unsigned short)v1[i] << 16));
            }
        }
        __syncthreads();

        short8 pf[2];
        #pragma unroll
        for (int ks = 0; ks < 2; ++ks)
            pf[ks] = *(const short8*)&Pt[(wave * 16 + c) * LDP + ks * 32 + quad * 8];
        #pragma unroll
        for (int nb = 0; nb < 4; ++nb) {
            float4v acc = o[nb];
            #pragma unroll
            for (int ks = 0; ks < 2; ++ks) {
                const int d = nb * 16 + c;
                const int kch = ks * 4 + quad;
                const int col = ((kch ^ (d >> 3)) << 3);
                short8 vfrag = *(const short8*)&Vt[d * LDP + col];
                acc = __builtin_amdgcn_mfma_f32_16x16x32_bf16(pf[ks], vfrag, acc, 0, 0, 0);
            }
            o[nb] = acc;
        }
    }

    #pragma unroll
    for (int r = 0; r < 4; ++r) {
        const float inv = 1.0f / l_r[r];
        const int row = i0 + wave * 16 + quad * 4 + r;
        #pragma unroll
        for (int nb = 0; nb < 4; ++nb)
            attn_bf[((size_t)b * SEQ + row) * EMB + h * 64 + nb * 16 + c] =
                f2bf(o[nb][r] * inv);
    }
}

// ---------------------------------------------------------------------------
// K3a: Wo^T bf16 prep (64x64 LDS transpose tiles).
// ---------------------------------------------------------------------------
__global__ __launch_bounds__(256) void wot_prep(
    const float* __restrict__ Wo, unsigned short* __restrict__ BT)
{
    __shared__ unsigned short Ws[64][72];
    const int k0 = blockIdx.y * 64, n0 = blockIdx.x * 64;
    const int t = threadIdx.x;
    #pragma unroll
    for (int it = 0; it < 4; ++it) {
        const int idx = it * 256 + t;
        const int r = idx >> 4, c4 = (idx & 15) * 4;
        const float4 w4 = *(const float4*)&Wo[(size_t)(k0 + r) * EMB + n0 + c4];
        Ws[r][c4 + 0] = f2bf(w4.x); Ws[r][c4 + 1] = f2bf(w4.y);
        Ws[r][c4 + 2] = f2bf(w4.z); Ws[r][c4 + 3] = f2bf(w4.w);
    }
    __syncthreads();
    #pragma unroll
    for (int it = 0; it < 2; ++it) {
        const int idx = it * 256 + t;
        const int n = idx >> 3, k8 = (idx & 7) * 8;
        short8 pack;
        #pragma unroll
        for (int j = 0; j < 8; ++j) pack[j] = (short)Ws[k8 + j][n];
        *(short8*)&BT[(size_t)(n0 + n) * EMB + k0 + k8] = pack;
    }
}

// ---------------------------------------------------------------------------
// K3b: out = attn_bf @ Wo + bo via bf16 MFMA, frags direct from global (L2).
// ---------------------------------------------------------------------------
__global__ __launch_bounds__(256) void out_gemm_kernel(
    const unsigned short* __restrict__ A,   // [4096][512] bf16
    const unsigned short* __restrict__ BT,  // [512][512] bf16, [n][k]
    const float* __restrict__ bias, float* __restrict__ out)
{
    const int tid  = threadIdx.x;
    const int lane = tid & 63, wave = tid >> 6;
    const int qd = lane >> 4, c = lane & 15;
    const int wm = (wave & 1) * 32, wn = (wave >> 1) * 32;
    const int row0 = blockIdx.y * 64, col0 = blockIdx.x * 64;

    float4v acc[2][2];
    #pragma unroll
    for (int i = 0; i < 2; ++i)
        #pragma unroll
        for (int j = 0; j < 2; ++j)
            acc[i][j] = (float4v){0.f, 0.f, 0.f, 0.f};

    for (int k0 = 0; k0 < EMB; k0 += 32) {
        short8 af[2], bf[2];
        #pragma unroll
        for (int i = 0; i < 2; ++i)
            af[i] = *(const short8*)&A[(size_t)(row0 + wm + i * 16 + c) * EMB + k0 + qd * 8];
        #pragma unroll
        for (int j = 0; j < 2; ++j)
            bf[j] = *(const short8*)&BT[(size_t)(col0 + wn + j * 16 + c) * EMB + k0 + qd * 8];
        #pragma unroll
        for (int i = 0; i < 2; ++i)
            #pragma unroll
            for (int j = 0; j < 2; ++j)
                acc[i][j] = __builtin_amdgcn_mfma_f32_16x16x32_bf16(af[i], bf[j], acc[i][j], 0, 0, 0);
    }

    #pragma unroll
    for (int i = 0; i < 2; ++i)
        #pragma unroll
        for (int r = 0; r < 4; ++r) {
            const int gm = row0 + wm + i * 16 + qd * 4 + r;
            #pragma unroll
            for (int j = 0; j < 2; ++j) {
                const int gn = col0 + wn + j * 16 + c;
                out[(size_t)gm * EMB + gn] = acc[i][j][r] + bias[gn];
            }
        }
}

// ---------------------------------------------------------------------------
extern "C" void kernel_launch(void* const* d_in, const int* in_sizes, int n_in,
                              void* d_out, int out_size, void* d_ws, size_t ws_size,
                              hipStream_t stream)
{
    const float* x   = (const float*)d_in[0];
    const float* Wq  = (const float*)d_in[1];
    const float* Wk  = (const float*)d_in[2];
    const float* Wv  = (const float*)d_in[3];
    const float* Wo  = (const float*)d_in[4];
    const float* bo  = (const float*)d_in[5];
    const float* gW1 = (const float*)d_in[6];
    const float* gb1 = (const float*)d_in[7];
    const float* gg  = (const float*)d_in[8];
    const float* gbe = (const float*)d_in[9];
    const float* gW2 = (const float*)d_in[10];
    const float* gb2 = (const float*)d_in[11];
    const float* gW3 = (const float*)d_in[12];
    const float* gb3 = (const float*)d_in[13];
    const float* cW1 = (const float*)d_in[14];
    const float* cb1 = (const float*)d_in[15];
    const float* cg  = (const float*)d_in[16];
    const float* cbe = (const float*)d_in[17];
    const float* cW2 = (const float*)d_in[18];
    const float* cb2 = (const float*)d_in[19];
    const float* cW3 = (const float*)d_in[20];
    const float* cb3 = (const float*)d_in[21];
    const float* aq  = (const float*)d_in[22];
    const float* bq  = (const float*)d_in[23];
    const float* ak  = (const float*)d_in[24];
    const float* bk  = (const float*)d_in[25];
    const float* av  = (const float*)d_in[26];
    const float* bv  = (const float*)d_in[27];

    int* Tp = (int*)d_ws;
    unsigned short* q_sum   = (unsigned short*)((char*)d_ws + 16384);
    unsigned short* k_sum   = q_sum   + (size_t)NROWS * EMB;
    unsigned short* v_mean  = k_sum   + (size_t)NROWS * EMB;
    unsigned short* attn_bf = v_mean  + (size_t)NROWS * EMB;
    unsigned short* WoT     = attn_bf + (size_t)NROWS * EMB;
    float* out = (float*)d_out;

    gates_kernel<<<dim3(NROWS / GROWS), dim3(256), 0, stream>>>(
        x, gW1, gb1, gg, gbe, gW2, gb2, gW3, gb3,
        cW1, cb1, cg, cbe, cW2, cb2, cW3, cb3, Tp);

    qkv_lif_kernel<<<dim3(EMB / 64, NROWS / 128, 3), dim3(256), 0, stream>>>(
        x, Wq, Wk, Wv, aq, bq, ak, bk, av, bv, Tp, q_sum, k_sum, v_mean);

    wot_prep<<<dim3(EMB / 64, EMB / 64), dim3(256), 0, stream>>>(Wo, WoT);

    attn_mfma_kernel<<<dim3(SEQ / 64, 8, 4), dim3(256), 0, stream>>>(
        q_sum, k_sum, v_mean, attn_bf);

    out_gemm_kernel<<<dim3(EMB / 64, NROWS / 64), dim3(256), 0, stream>>>(
        attn_bf, WoT, bo, out);
}